// Round 1
// baseline (1962.471 us; speedup 1.0000x reference)
//
#include <hip/hip_runtime.h>
#include <cstddef>

#define EE 1024            // E
#define MTOT 8192          // B*E

__device__ __forceinline__ float elu1(float x) {
    // elu(x)+1 : x>0 -> x+1 ; else exp(x)
    return x > 0.f ? x + 1.f : __expf(x);
}

__device__ __forceinline__ void fma_col(float (&acc)[4][4],
                                        float a0, float a1, float a2, float a3,
                                        const float4 b) {
    acc[0][0] += a0 * b.x; acc[0][1] += a0 * b.y; acc[0][2] += a0 * b.z; acc[0][3] += a0 * b.w;
    acc[1][0] += a1 * b.x; acc[1][1] += a1 * b.y; acc[1][2] += a1 * b.z; acc[1][3] += a1 * b.w;
    acc[2][0] += a2 * b.x; acc[2][1] += a2 * b.y; acc[2][2] += a2 * b.z; acc[2][3] += a2 * b.w;
    acc[3][0] += a3 * b.x; acc[3][1] += a3 * b.y; acc[3][2] += a3 * b.z; acc[3][3] += a3 * b.w;
}

// C[m][j] = sum_k A[m][k] * W[j][k] + bias[j]
// A: [MTOT][K], W: [1024][K], C: [MTOT][1024]. Both operands K-contiguous (A@B^T).
template<int K>
__global__ __launch_bounds__(256)
void gemm_abt(const float* __restrict__ A, const float* __restrict__ W,
              const float* __restrict__ bias, float* __restrict__ C) {
    __shared__ __align__(16) float As[16][68];   // K-major: As[k][m]
    __shared__ __align__(16) float Ws[16][68];   // K-major: Ws[k][j]
    const int t  = threadIdx.x;
    const int tx = t & 15, ty = t >> 4;
    const int r0 = ty * 4, c0 = tx * 4;
    const int m0 = blockIdx.y * 64;
    const int j0 = blockIdx.x * 64;
    const int lr = t >> 2;          // 0..63 : tile row being staged
    const int lk = (t & 3) * 4;     // 0,4,8,12 : k offset being staged
    const float* Ap = A + (size_t)(m0 + lr) * K + lk;
    const float* Wp = W + (size_t)(j0 + lr) * K + lk;
    float acc[4][4] = {{0.f}};
    for (int kb = 0; kb < K; kb += 16) {
        const float4 av = *(const float4*)(Ap + kb);
        const float4 wv = *(const float4*)(Wp + kb);
        As[lk + 0][lr] = av.x; As[lk + 1][lr] = av.y;
        As[lk + 2][lr] = av.z; As[lk + 3][lr] = av.w;
        Ws[lk + 0][lr] = wv.x; Ws[lk + 1][lr] = wv.y;
        Ws[lk + 2][lr] = wv.z; Ws[lk + 3][lr] = wv.w;
        __syncthreads();
        #pragma unroll
        for (int kk = 0; kk < 16; ++kk) {
            const float4 a4 = *(const float4*)&As[kk][r0];
            const float4 b4 = *(const float4*)&Ws[kk][c0];
            fma_col(acc, a4.x, a4.y, a4.z, a4.w, b4);
        }
        __syncthreads();
    }
    const float4 bi = *(const float4*)(bias + j0 + c0);
    #pragma unroll
    for (int i = 0; i < 4; ++i) {
        float4 o;
        o.x = acc[i][0] + bi.x; o.y = acc[i][1] + bi.y;
        o.z = acc[i][2] + bi.z; o.w = acc[i][3] + bi.w;
        *(float4*)(C + (size_t)(m0 + r0 + i) * EE + j0 + c0) = o;
    }
}

// One workgroup per (b,h): sequential scan over 16 segments.
// q buffer is overwritten in place with the attention output.
__global__ __launch_bounds__(256)
void attn_scan(float* __restrict__ q, const float* __restrict__ k,
               const float* __restrict__ v, const float* __restrict__ beta) {
    __shared__ __align__(16) float Lq[64 * 68];   // raw q tile
    __shared__ __align__(16) float Lk[64 * 68];   // raw k tile
    __shared__ __align__(16) float Lv[64 * 68];   // raw v tile
    __shared__ __align__(16) float Lm[64 * 68];   // mem carry [d][e]
    __shared__ __align__(16) float Lp[64 * 68];   // softmax P
    __shared__ __align__(16) float Ls[64 * 68];   // sigma_q then sigma_k
    __shared__ float rs[64];                      // rowsum of sigma_q
    __shared__ float zr[64];                      // z carry
    const int t  = threadIdx.x;
    const int tx = t & 15, ty = t >> 4;
    const int r0 = ty * 4, c0 = tx * 4;
    const int b  = blockIdx.x >> 4, h = blockIdx.x & 15;
    const float gate = 1.f / (1.f + __expf(-10.f * beta[h]));
    const float omg  = 1.f - gate;

    for (int i = t; i < 64 * 68; i += 256) Lm[i] = 0.f;
    if (t < 64) zr[t] = 0.f;
    __syncthreads();

    const size_t hb = (size_t)b * (size_t)(EE * EE) + (size_t)h * 65536;
    for (int n = 0; n < 16; ++n) {
        const size_t base = hb + (size_t)n * 4096;
        // ---- stage q,k,v tiles (64x64 contiguous) into padded LDS
        #pragma unroll
        for (int i = 0; i < 4; ++i) {
            const int f  = t + i * 256;                 // float4 index 0..1023
            const int ld = (f >> 4) * 68 + (f & 15) * 4;
            *(float4*)&Lq[ld] = *(const float4*)(q + base + f * 4);
            *(float4*)&Lk[ld] = *(const float4*)(k + base + f * 4);
            *(float4*)&Lv[ld] = *(const float4*)(v + base + f * 4);
        }
        __syncthreads();
        // ---- sigma_q = elu(q)+1
        #pragma unroll
        for (int i = 0; i < 4; ++i) {
            const int f  = t + i * 256;
            const int ld = (f >> 4) * 68 + (f & 15) * 4;
            float4 a = *(const float4*)&Lq[ld];
            a.x = elu1(a.x); a.y = elu1(a.y); a.z = elu1(a.z); a.w = elu1(a.w);
            *(float4*)&Ls[ld] = a;
        }
        __syncthreads();
        // ---- rowsums of sigma_q (needed post-barrier)
        if (t < 64) {
            float s = 0.f;
            #pragma unroll
            for (int j = 0; j < 64; j += 4) {
                const float4 a = *(const float4*)&Ls[t * 68 + j];
                s += a.x + a.y + a.z + a.w;
            }
            rs[t] = s;
        }
        // ---- scores = q k^T, causal softmax (scale 1/8) -> Lp
        {
            float sc[4][4] = {{0.f}};
            #pragma unroll 4
            for (int kk = 0; kk < 64; kk += 4) {
                float4 aq0 = *(const float4*)&Lq[(r0 + 0) * 68 + kk];
                float4 aq1 = *(const float4*)&Lq[(r0 + 1) * 68 + kk];
                float4 aq2 = *(const float4*)&Lq[(r0 + 2) * 68 + kk];
                float4 aq3 = *(const float4*)&Lq[(r0 + 3) * 68 + kk];
                float4 bk0 = *(const float4*)&Lk[(c0 + 0) * 68 + kk];
                float4 bk1 = *(const float4*)&Lk[(c0 + 1) * 68 + kk];
                float4 bk2 = *(const float4*)&Lk[(c0 + 2) * 68 + kk];
                float4 bk3 = *(const float4*)&Lk[(c0 + 3) * 68 + kk];
                fma_col(sc, aq0.x, aq1.x, aq2.x, aq3.x, make_float4(bk0.x, bk1.x, bk2.x, bk3.x));
                fma_col(sc, aq0.y, aq1.y, aq2.y, aq3.y, make_float4(bk0.y, bk1.y, bk2.y, bk3.y));
                fma_col(sc, aq0.z, aq1.z, aq2.z, aq3.z, make_float4(bk0.z, bk1.z, bk2.z, bk3.z));
                fma_col(sc, aq0.w, aq1.w, aq2.w, aq3.w, make_float4(bk0.w, bk1.w, bk2.w, bk3.w));
            }
            #pragma unroll
            for (int i = 0; i < 4; ++i) {
                const int r = r0 + i;
                float m = -3.0e38f;
                #pragma unroll
                for (int j = 0; j < 4; ++j) {
                    sc[i][j] = (c0 + j <= r) ? sc[i][j] * 0.125f : -3.0e38f;
                    m = fmaxf(m, sc[i][j]);
                }
                #pragma unroll
                for (int off = 1; off < 16; off <<= 1)
                    m = fmaxf(m, __shfl_xor(m, off, 64));
                float ssum = 0.f;
                #pragma unroll
                for (int j = 0; j < 4; ++j) {
                    sc[i][j] = (c0 + j <= r) ? __expf(sc[i][j] - m) : 0.f;
                    ssum += sc[i][j];
                }
                #pragma unroll
                for (int off = 1; off < 16; off <<= 1)
                    ssum += __shfl_xor(ssum, off, 64);
                const float inv = 1.f / ssum;
                float4 p;
                p.x = sc[i][0] * inv; p.y = sc[i][1] * inv;
                p.z = sc[i][2] * inv; p.w = sc[i][3] * inv;
                *(float4*)&Lp[r * 68 + c0] = p;
            }
        }
        __syncthreads();
        // ---- A_dot = P@V ; A_mem = (sigma_q@mem)/denom ; combine ; store attn over q
        {
            float ad[4][4] = {{0.f}};
            #pragma unroll 4
            for (int c = 0; c < 64; ++c) {
                const float4 vv = *(const float4*)&Lv[c * 68 + c0];
                const float p0 = Lp[(r0 + 0) * 68 + c];
                const float p1 = Lp[(r0 + 1) * 68 + c];
                const float p2 = Lp[(r0 + 2) * 68 + c];
                const float p3 = Lp[(r0 + 3) * 68 + c];
                fma_col(ad, p0, p1, p2, p3, vv);
            }
            float am[4][4] = {{0.f}};
            #pragma unroll 4
            for (int kk = 0; kk < 64; kk += 4) {
                float4 a0 = *(const float4*)&Ls[(r0 + 0) * 68 + kk];
                float4 a1 = *(const float4*)&Ls[(r0 + 1) * 68 + kk];
                float4 a2 = *(const float4*)&Ls[(r0 + 2) * 68 + kk];
                float4 a3 = *(const float4*)&Ls[(r0 + 3) * 68 + kk];
                float4 m0 = *(const float4*)&Lm[(kk + 0) * 68 + c0];
                float4 m1 = *(const float4*)&Lm[(kk + 1) * 68 + c0];
                float4 m2 = *(const float4*)&Lm[(kk + 2) * 68 + c0];
                float4 m3 = *(const float4*)&Lm[(kk + 3) * 68 + c0];
                fma_col(am, a0.x, a1.x, a2.x, a3.x, m0);
                fma_col(am, a0.y, a1.y, a2.y, a3.y, m1);
                fma_col(am, a0.z, a1.z, a2.z, a3.z, m2);
                fma_col(am, a0.w, a1.w, a2.w, a3.w, m3);
            }
            const float4 z4 = *(const float4*)&zr[c0];
            #pragma unroll
            for (int i = 0; i < 4; ++i) {
                const float rsum = rs[r0 + i];
                float4 o;
                o.x = gate * (am[i][0] / (rsum * z4.x + 1e-6f)) + omg * ad[i][0];
                o.y = gate * (am[i][1] / (rsum * z4.y + 1e-6f)) + omg * ad[i][1];
                o.z = gate * (am[i][2] / (rsum * z4.z + 1e-6f)) + omg * ad[i][2];
                o.w = gate * (am[i][3] / (rsum * z4.w + 1e-6f)) + omg * ad[i][3];
                *(float4*)(q + base + (size_t)(r0 + i) * 64 + c0) = o;
            }
        }
        __syncthreads();
        // ---- sigma_k = elu(k)+1 -> Ls (sigma_q no longer needed)
        #pragma unroll
        for (int i = 0; i < 4; ++i) {
            const int f  = t + i * 256;
            const int ld = (f >> 4) * 68 + (f & 15) * 4;
            float4 a = *(const float4*)&Lk[ld];
            a.x = elu1(a.x); a.y = elu1(a.y); a.z = elu1(a.z); a.w = elu1(a.w);
            *(float4*)&Ls[ld] = a;
        }
        __syncthreads();
        // ---- mem += sigma_k^T @ v ; z += colsum(sigma_k)
        {
            float mu[4][4] = {{0.f}};
            #pragma unroll 4
            for (int s = 0; s < 64; ++s) {
                const float4 sk4 = *(const float4*)&Ls[s * 68 + r0];
                const float4 vv4 = *(const float4*)&Lv[s * 68 + c0];
                fma_col(mu, sk4.x, sk4.y, sk4.z, sk4.w, vv4);
            }
            #pragma unroll
            for (int i = 0; i < 4; ++i) {
                float4 cur = *(const float4*)&Lm[(r0 + i) * 68 + c0];
                cur.x += mu[i][0]; cur.y += mu[i][1];
                cur.z += mu[i][2]; cur.w += mu[i][3];
                *(float4*)&Lm[(r0 + i) * 68 + c0] = cur;
            }
            if (t < 64) {
                float a = 0.f;
                #pragma unroll 8
                for (int s = 0; s < 64; ++s) a += Ls[s * 68 + t];
                zr[t] += a;
            }
        }
        __syncthreads();
    }
}

extern "C" void kernel_launch(void* const* d_in, const int* in_sizes, int n_in,
                              void* d_out, int out_size, void* d_ws, size_t ws_size,
                              hipStream_t stream) {
    const float* x    = (const float*)d_in[0];
    const float* Wq   = (const float*)d_in[1];
    const float* bq   = (const float*)d_in[2];
    const float* Wk   = (const float*)d_in[3];
    const float* bk   = (const float*)d_in[4];
    const float* Wv   = (const float*)d_in[5];
    const float* bv   = (const float*)d_in[6];
    const float* Wo   = (const float*)d_in[7];
    const float* bo   = (const float*)d_in[8];
    const float* beta = (const float*)d_in[9];
    float* out = (float*)d_out;

    float* qb = (float*)d_ws;                    // [8192][1024] -> becomes attn
    float* kb = qb + (size_t)MTOT * EE;
    float* vb = kb + (size_t)MTOT * EE;

    dim3 grid(EE / 64, MTOT / 64);
    gemm_abt<2048><<<grid, 256, 0, stream>>>(x, Wq, bq, qb);
    gemm_abt<2048><<<grid, 256, 0, stream>>>(x, Wk, bk, kb);
    gemm_abt<2048><<<grid, 256, 0, stream>>>(x, Wv, bv, vb);
    attn_scan<<<128, 256, 0, stream>>>(qb, kb, vb, beta);
    gemm_abt<1024><<<grid, 256, 0, stream>>>(qb, Wo, bo, out);
}

// Round 2
// 675.854 us; speedup vs baseline: 2.9037x; 2.9037x over previous
//
#include <hip/hip_runtime.h>
#include <hip/hip_bf16.h>
#include <cstddef>

#define EE 1024            // E
#define MTOT 8192          // B*E

using floatx4 = __attribute__((ext_vector_type(4))) float;
using bf16x8  = __attribute__((ext_vector_type(8))) __bf16;

union FragU { uint4 u; bf16x8 b; };

__device__ __forceinline__ float elu1(float x) {
    return x > 0.f ? x + 1.f : __expf(x);
}

__device__ __forceinline__ unsigned int pack2bf(float x, float y) {
    __hip_bfloat162 h = __float22bfloat162_rn(make_float2(x, y));
    union { __hip_bfloat162 h; unsigned int u; } c;
    c.h = h;
    return c.u;
}

__device__ __forceinline__ uint4 pack8bf(const float4 a, const float4 b) {
    uint4 r;
    r.x = pack2bf(a.x, a.y); r.y = pack2bf(a.z, a.w);
    r.z = pack2bf(b.x, b.y); r.w = pack2bf(b.z, b.w);
    return r;
}

// C[m][j] = sum_k A[m][k] * W[j][k] + bias[j]   (A @ W^T)
// A: [MTOT][K] fp32, W: [1024][K] fp32, C: [MTOT][1024] fp32.
// bf16 MFMA 16x16x32, 128x128 block tile, BK=32, 4 waves of 64x64.
template<int K>
__global__ __launch_bounds__(256)
void gemm_mfma(const float* __restrict__ A, const float* __restrict__ W,
               const float* __restrict__ bias, float* __restrict__ C) {
    constexpr int LDT = 40;                       // bf16 elems per LDS row (32 used + pad)
    __shared__ __align__(16) unsigned short As[128 * LDT];
    __shared__ __align__(16) unsigned short Bs[128 * LDT];

    const int t  = threadIdx.x;
    const int m0 = blockIdx.y * 128;
    const int n0 = blockIdx.x * 128;
    const int w  = t >> 6, l = t & 63;
    const int wm = (w >> 1) * 64;                 // wave M offset in tile
    const int wn = (w & 1) * 64;                  // wave N offset in tile
    const int lm = l & 15, lq = l >> 4;           // lane -> fragment row / k-quad

    // staging assignment: thread t loads 16 contiguous fp32 of one row
    const int row  = t >> 1;                      // 0..127
    const int half = t & 1;                       // 0 / 1 -> k offset 0 / 16
    const float* Ap = A + (size_t)(m0 + row) * K + half * 16;
    const float* Wp = W + (size_t)(n0 + row) * K + half * 16;
    unsigned short* Asw = &As[row * LDT + half * 16];
    unsigned short* Bsw = &Bs[row * LDT + half * 16];

    floatx4 acc[4][4];
    #pragma unroll
    for (int i = 0; i < 4; ++i)
        #pragma unroll
        for (int j = 0; j < 4; ++j)
            acc[i][j] = (floatx4)(0.f);

    for (int kb = 0; kb < K; kb += 32) {
        const float4 a0 = *(const float4*)(Ap + kb);
        const float4 a1 = *(const float4*)(Ap + kb + 4);
        const float4 a2 = *(const float4*)(Ap + kb + 8);
        const float4 a3 = *(const float4*)(Ap + kb + 12);
        const float4 b0 = *(const float4*)(Wp + kb);
        const float4 b1 = *(const float4*)(Wp + kb + 4);
        const float4 b2 = *(const float4*)(Wp + kb + 8);
        const float4 b3 = *(const float4*)(Wp + kb + 12);
        const uint4 pa0 = pack8bf(a0, a1), pa1 = pack8bf(a2, a3);
        const uint4 pb0 = pack8bf(b0, b1), pb1 = pack8bf(b2, b3);
        __syncthreads();                          // previous iter's frag reads done
        *(uint4*)(Asw + 0) = pa0;
        *(uint4*)(Asw + 8) = pa1;
        *(uint4*)(Bsw + 0) = pb0;
        *(uint4*)(Bsw + 8) = pb1;
        __syncthreads();
        FragU af[4], bf[4];
        #pragma unroll
        for (int i = 0; i < 4; ++i)
            af[i].u = *(const uint4*)&As[(wm + i * 16 + lm) * LDT + lq * 8];
        #pragma unroll
        for (int j = 0; j < 4; ++j)
            bf[j].u = *(const uint4*)&Bs[(wn + j * 16 + lm) * LDT + lq * 8];
        #pragma unroll
        for (int i = 0; i < 4; ++i)
            #pragma unroll
            for (int j = 0; j < 4; ++j)
                acc[i][j] = __builtin_amdgcn_mfma_f32_16x16x32_bf16(
                    af[i].b, bf[j].b, acc[i][j], 0, 0, 0);
    }

    #pragma unroll
    for (int j = 0; j < 4; ++j) {
        const int col = n0 + wn + j * 16 + lm;
        const float bj = bias[col];
        #pragma unroll
        for (int i = 0; i < 4; ++i) {
            #pragma unroll
            for (int r = 0; r < 4; ++r) {
                const int rrow = m0 + wm + i * 16 + lq * 4 + r;
                C[(size_t)rrow * EE + col] = acc[i][j][r] + bj;
            }
        }
    }
}

__device__ __forceinline__ void fma_col(float (&acc)[4][4],
                                        float a0, float a1, float a2, float a3,
                                        const float4 b) {
    acc[0][0] += a0 * b.x; acc[0][1] += a0 * b.y; acc[0][2] += a0 * b.z; acc[0][3] += a0 * b.w;
    acc[1][0] += a1 * b.x; acc[1][1] += a1 * b.y; acc[1][2] += a1 * b.z; acc[1][3] += a1 * b.w;
    acc[2][0] += a2 * b.x; acc[2][1] += a2 * b.y; acc[2][2] += a2 * b.z; acc[2][3] += a2 * b.w;
    acc[3][0] += a3 * b.x; acc[3][1] += a3 * b.y; acc[3][2] += a3 * b.z; acc[3][3] += a3 * b.w;
}

// One workgroup per (b,h): sequential scan over 16 segments.
// q buffer is overwritten in place with the attention output.
__global__ __launch_bounds__(256)
void attn_scan(float* __restrict__ q, const float* __restrict__ k,
               const float* __restrict__ v, const float* __restrict__ beta) {
    __shared__ __align__(16) float Lq[64 * 68];
    __shared__ __align__(16) float Lk[64 * 68];
    __shared__ __align__(16) float Lv[64 * 68];
    __shared__ __align__(16) float Lm[64 * 68];
    __shared__ __align__(16) float Lp[64 * 68];
    __shared__ __align__(16) float Ls[64 * 68];
    __shared__ float rs[64];
    __shared__ float zr[64];
    const int t  = threadIdx.x;
    const int tx = t & 15, ty = t >> 4;
    const int r0 = ty * 4, c0 = tx * 4;
    const int b  = blockIdx.x >> 4, h = blockIdx.x & 15;
    const float gate = 1.f / (1.f + __expf(-10.f * beta[h]));
    const float omg  = 1.f - gate;

    for (int i = t; i < 64 * 68; i += 256) Lm[i] = 0.f;
    if (t < 64) zr[t] = 0.f;
    __syncthreads();

    const size_t hb = (size_t)b * (size_t)(EE * EE) + (size_t)h * 65536;
    for (int n = 0; n < 16; ++n) {
        const size_t base = hb + (size_t)n * 4096;
        #pragma unroll
        for (int i = 0; i < 4; ++i) {
            const int f  = t + i * 256;
            const int ld = (f >> 4) * 68 + (f & 15) * 4;
            *(float4*)&Lq[ld] = *(const float4*)(q + base + f * 4);
            *(float4*)&Lk[ld] = *(const float4*)(k + base + f * 4);
            *(float4*)&Lv[ld] = *(const float4*)(v + base + f * 4);
        }
        __syncthreads();
        #pragma unroll
        for (int i = 0; i < 4; ++i) {
            const int f  = t + i * 256;
            const int ld = (f >> 4) * 68 + (f & 15) * 4;
            float4 a = *(const float4*)&Lq[ld];
            a.x = elu1(a.x); a.y = elu1(a.y); a.z = elu1(a.z); a.w = elu1(a.w);
            *(float4*)&Ls[ld] = a;
        }
        __syncthreads();
        if (t < 64) {
            float s = 0.f;
            #pragma unroll
            for (int j = 0; j < 64; j += 4) {
                const float4 a = *(const float4*)&Ls[t * 68 + j];
                s += a.x + a.y + a.z + a.w;
            }
            rs[t] = s;
        }
        {
            float sc[4][4] = {{0.f}};
            #pragma unroll 4
            for (int kk = 0; kk < 64; kk += 4) {
                float4 aq0 = *(const float4*)&Lq[(r0 + 0) * 68 + kk];
                float4 aq1 = *(const float4*)&Lq[(r0 + 1) * 68 + kk];
                float4 aq2 = *(const float4*)&Lq[(r0 + 2) * 68 + kk];
                float4 aq3 = *(const float4*)&Lq[(r0 + 3) * 68 + kk];
                float4 bk0 = *(const float4*)&Lk[(c0 + 0) * 68 + kk];
                float4 bk1 = *(const float4*)&Lk[(c0 + 1) * 68 + kk];
                float4 bk2 = *(const float4*)&Lk[(c0 + 2) * 68 + kk];
                float4 bk3 = *(const float4*)&Lk[(c0 + 3) * 68 + kk];
                fma_col(sc, aq0.x, aq1.x, aq2.x, aq3.x, make_float4(bk0.x, bk1.x, bk2.x, bk3.x));
                fma_col(sc, aq0.y, aq1.y, aq2.y, aq3.y, make_float4(bk0.y, bk1.y, bk2.y, bk3.y));
                fma_col(sc, aq0.z, aq1.z, aq2.z, aq3.z, make_float4(bk0.z, bk1.z, bk2.z, bk3.z));
                fma_col(sc, aq0.w, aq1.w, aq2.w, aq3.w, make_float4(bk0.w, bk1.w, bk2.w, bk3.w));
            }
            #pragma unroll
            for (int i = 0; i < 4; ++i) {
                const int r = r0 + i;
                float m = -3.0e38f;
                #pragma unroll
                for (int j = 0; j < 4; ++j) {
                    sc[i][j] = (c0 + j <= r) ? sc[i][j] * 0.125f : -3.0e38f;
                    m = fmaxf(m, sc[i][j]);
                }
                #pragma unroll
                for (int off = 1; off < 16; off <<= 1)
                    m = fmaxf(m, __shfl_xor(m, off, 64));
                float ssum = 0.f;
                #pragma unroll
                for (int j = 0; j < 4; ++j) {
                    sc[i][j] = (c0 + j <= r) ? __expf(sc[i][j] - m) : 0.f;
                    ssum += sc[i][j];
                }
                #pragma unroll
                for (int off = 1; off < 16; off <<= 1)
                    ssum += __shfl_xor(ssum, off, 64);
                const float inv = 1.f / ssum;
                float4 p;
                p.x = sc[i][0] * inv; p.y = sc[i][1] * inv;
                p.z = sc[i][2] * inv; p.w = sc[i][3] * inv;
                *(float4*)&Lp[r * 68 + c0] = p;
            }
        }
        __syncthreads();
        {
            float ad[4][4] = {{0.f}};
            #pragma unroll 4
            for (int c = 0; c < 64; ++c) {
                const float4 vv = *(const float4*)&Lv[c * 68 + c0];
                const float p0 = Lp[(r0 + 0) * 68 + c];
                const float p1 = Lp[(r0 + 1) * 68 + c];
                const float p2 = Lp[(r0 + 2) * 68 + c];
                const float p3 = Lp[(r0 + 3) * 68 + c];
                fma_col(ad, p0, p1, p2, p3, vv);
            }
            float am[4][4] = {{0.f}};
            #pragma unroll 4
            for (int kk = 0; kk < 64; kk += 4) {
                float4 a0 = *(const float4*)&Ls[(r0 + 0) * 68 + kk];
                float4 a1 = *(const float4*)&Ls[(r0 + 1) * 68 + kk];
                float4 a2 = *(const float4*)&Ls[(r0 + 2) * 68 + kk];
                float4 a3 = *(const float4*)&Ls[(r0 + 3) * 68 + kk];
                float4 m0 = *(const float4*)&Lm[(kk + 0) * 68 + c0];
                float4 m1 = *(const float4*)&Lm[(kk + 1) * 68 + c0];
                float4 m2 = *(const float4*)&Lm[(kk + 2) * 68 + c0];
                float4 m3 = *(const float4*)&Lm[(kk + 3) * 68 + c0];
                fma_col(am, a0.x, a1.x, a2.x, a3.x, m0);
                fma_col(am, a0.y, a1.y, a2.y, a3.y, m1);
                fma_col(am, a0.z, a1.z, a2.z, a3.z, m2);
                fma_col(am, a0.w, a1.w, a2.w, a3.w, m3);
            }
            const float4 z4 = *(const float4*)&zr[c0];
            #pragma unroll
            for (int i = 0; i < 4; ++i) {
                const float rsum = rs[r0 + i];
                float4 o;
                o.x = gate * (am[i][0] / (rsum * z4.x + 1e-6f)) + omg * ad[i][0];
                o.y = gate * (am[i][1] / (rsum * z4.y + 1e-6f)) + omg * ad[i][1];
                o.z = gate * (am[i][2] / (rsum * z4.z + 1e-6f)) + omg * ad[i][2];
                o.w = gate * (am[i][3] / (rsum * z4.w + 1e-6f)) + omg * ad[i][3];
                *(float4*)(q + base + (size_t)(r0 + i) * 64 + c0) = o;
            }
        }
        __syncthreads();
        #pragma unroll
        for (int i = 0; i < 4; ++i) {
            const int f  = t + i * 256;
            const int ld = (f >> 4) * 68 + (f & 15) * 4;
            float4 a = *(const float4*)&Lk[ld];
            a.x = elu1(a.x); a.y = elu1(a.y); a.z = elu1(a.z); a.w = elu1(a.w);
            *(float4*)&Ls[ld] = a;
        }
        __syncthreads();
        {
            float mu[4][4] = {{0.f}};
            #pragma unroll 4
            for (int s = 0; s < 64; ++s) {
                const float4 sk4 = *(const float4*)&Ls[s * 68 + r0];
                const float4 vv4 = *(const float4*)&Lv[s * 68 + c0];
                fma_col(mu, sk4.x, sk4.y, sk4.z, sk4.w, vv4);
            }
            #pragma unroll
            for (int i = 0; i < 4; ++i) {
                float4 cur = *(const float4*)&Lm[(r0 + i) * 68 + c0];
                cur.x += mu[i][0]; cur.y += mu[i][1];
                cur.z += mu[i][2]; cur.w += mu[i][3];
                *(float4*)&Lm[(r0 + i) * 68 + c0] = cur;
            }
            if (t < 64) {
                float a = 0.f;
                #pragma unroll 8
                for (int s = 0; s < 64; ++s) a += Ls[s * 68 + t];
                zr[t] += a;
            }
        }
        __syncthreads();
    }
}

extern "C" void kernel_launch(void* const* d_in, const int* in_sizes, int n_in,
                              void* d_out, int out_size, void* d_ws, size_t ws_size,
                              hipStream_t stream) {
    const float* x    = (const float*)d_in[0];
    const float* Wq   = (const float*)d_in[1];
    const float* bq   = (const float*)d_in[2];
    const float* Wk   = (const float*)d_in[3];
    const float* bk   = (const float*)d_in[4];
    const float* Wv   = (const float*)d_in[5];
    const float* bv   = (const float*)d_in[6];
    const float* Wo   = (const float*)d_in[7];
    const float* bo   = (const float*)d_in[8];
    const float* beta = (const float*)d_in[9];
    float* out = (float*)d_out;

    float* qb = (float*)d_ws;                    // [8192][1024] -> becomes attn
    float* kb = qb + (size_t)MTOT * EE;
    float* vb = kb + (size_t)MTOT * EE;

    dim3 grid(EE / 128, MTOT / 128);             // 8 x 64 = 512 blocks
    gemm_mfma<2048><<<grid, 256, 0, stream>>>(x, Wq, bq, qb);
    gemm_mfma<2048><<<grid, 256, 0, stream>>>(x, Wk, bk, kb);
    gemm_mfma<2048><<<grid, 256, 0, stream>>>(x, Wv, bv, vb);
    attn_scan<<<128, 256, 0, stream>>>(qb, kb, vb, beta);
    gemm_mfma<1024><<<grid, 256, 0, stream>>>(qb, Wo, bo, out);
}

// Round 3
// 591.928 us; speedup vs baseline: 3.3154x; 1.1418x over previous
//
#include <hip/hip_runtime.h>
#include <hip/hip_bf16.h>
#include <cstddef>

#define EE 1024            // E
#define MTOT 8192          // B*E

using floatx4 = __attribute__((ext_vector_type(4))) float;
using bf16x8  = __attribute__((ext_vector_type(8))) __bf16;

union FragU { uint4 u; bf16x8 b; };

__device__ __forceinline__ float elu1(float x) {
    return x > 0.f ? x + 1.f : __expf(x);
}

__device__ __forceinline__ unsigned int pack2bf(float x, float y) {
    __hip_bfloat162 h = __float22bfloat162_rn(make_float2(x, y));
    union { __hip_bfloat162 h; unsigned int u; } c;
    c.h = h;
    return c.u;
}

__device__ __forceinline__ uint4 pack8bf(const float4 a, const float4 b) {
    uint4 r;
    r.x = pack2bf(a.x, a.y); r.y = pack2bf(a.z, a.w);
    r.z = pack2bf(b.x, b.y); r.w = pack2bf(b.z, b.w);
    return r;
}

// C[m][j] = sum_k A[m][k] * W[j][k] + bias[j]   (A @ W^T)
// bf16 MFMA 16x16x32, 128x128 block tile, BK=32, 4 waves of 64x64.
template<int K>
__global__ __launch_bounds__(256)
void gemm_mfma(const float* __restrict__ A, const float* __restrict__ W,
               const float* __restrict__ bias, float* __restrict__ C) {
    constexpr int LDT = 40;
    __shared__ __align__(16) unsigned short As[128 * LDT];
    __shared__ __align__(16) unsigned short Bs[128 * LDT];

    const int t  = threadIdx.x;
    const int m0 = blockIdx.y * 128;
    const int n0 = blockIdx.x * 128;
    const int w  = t >> 6, l = t & 63;
    const int wm = (w >> 1) * 64;
    const int wn = (w & 1) * 64;
    const int lm = l & 15, lq = l >> 4;

    const int row  = t >> 1;
    const int half = t & 1;
    const float* Ap = A + (size_t)(m0 + row) * K + half * 16;
    const float* Wp = W + (size_t)(n0 + row) * K + half * 16;
    unsigned short* Asw = &As[row * LDT + half * 16];
    unsigned short* Bsw = &Bs[row * LDT + half * 16];

    floatx4 acc[4][4];
    #pragma unroll
    for (int i = 0; i < 4; ++i)
        #pragma unroll
        for (int j = 0; j < 4; ++j)
            acc[i][j] = (floatx4)(0.f);

    for (int kb = 0; kb < K; kb += 32) {
        const float4 a0 = *(const float4*)(Ap + kb);
        const float4 a1 = *(const float4*)(Ap + kb + 4);
        const float4 a2 = *(const float4*)(Ap + kb + 8);
        const float4 a3 = *(const float4*)(Ap + kb + 12);
        const float4 b0 = *(const float4*)(Wp + kb);
        const float4 b1 = *(const float4*)(Wp + kb + 4);
        const float4 b2 = *(const float4*)(Wp + kb + 8);
        const float4 b3 = *(const float4*)(Wp + kb + 12);
        const uint4 pa0 = pack8bf(a0, a1), pa1 = pack8bf(a2, a3);
        const uint4 pb0 = pack8bf(b0, b1), pb1 = pack8bf(b2, b3);
        __syncthreads();
        *(uint4*)(Asw + 0) = pa0;
        *(uint4*)(Asw + 8) = pa1;
        *(uint4*)(Bsw + 0) = pb0;
        *(uint4*)(Bsw + 8) = pb1;
        __syncthreads();
        FragU af[4], bf[4];
        #pragma unroll
        for (int i = 0; i < 4; ++i)
            af[i].u = *(const uint4*)&As[(wm + i * 16 + lm) * LDT + lq * 8];
        #pragma unroll
        for (int j = 0; j < 4; ++j)
            bf[j].u = *(const uint4*)&Bs[(wn + j * 16 + lm) * LDT + lq * 8];
        #pragma unroll
        for (int i = 0; i < 4; ++i)
            #pragma unroll
            for (int j = 0; j < 4; ++j)
                acc[i][j] = __builtin_amdgcn_mfma_f32_16x16x32_bf16(
                    af[i].b, bf[j].b, acc[i][j], 0, 0, 0);
    }

    #pragma unroll
    for (int j = 0; j < 4; ++j) {
        const int col = n0 + wn + j * 16 + lm;
        const float bj = bias[col];
        #pragma unroll
        for (int i = 0; i < 4; ++i) {
            #pragma unroll
            for (int r = 0; r < 4; ++r) {
                const int rrow = m0 + wm + i * 16 + lq * 4 + r;
                C[(size_t)rrow * EE + col] = acc[i][j][r] + bj;
            }
        }
    }
}

__device__ __forceinline__ void fma_col(float (&acc)[4][4],
                                        float a0, float a1, float a2, float a3,
                                        const float4 b) {
    acc[0][0] += a0 * b.x; acc[0][1] += a0 * b.y; acc[0][2] += a0 * b.z; acc[0][3] += a0 * b.w;
    acc[1][0] += a1 * b.x; acc[1][1] += a1 * b.y; acc[1][2] += a1 * b.z; acc[1][3] += a1 * b.w;
    acc[2][0] += a2 * b.x; acc[2][1] += a2 * b.y; acc[2][2] += a2 * b.z; acc[2][3] += a2 * b.w;
    acc[3][0] += a3 * b.x; acc[3][1] += a3 * b.y; acc[3][2] += a3 * b.z; acc[3][3] += a3 * b.w;
}

// ---- Stage 1: per-segment Sk = sigma_k^T @ v (64x64) and colsum(sigma_k).
// One block per (b,h,n) tile = 2048 blocks, fully parallel.
__global__ __launch_bounds__(256)
void seg_kv(const float* __restrict__ k, const float* __restrict__ v,
            float* __restrict__ Skv, float* __restrict__ zc) {
    __shared__ __align__(16) float Ls[64 * 68];   // sigma_k
    __shared__ __align__(16) float Lv[64 * 68];
    const int t  = threadIdx.x;
    const int tx = t & 15, ty = t >> 4;
    const int r0 = ty * 4, c0 = tx * 4;
    const size_t base = (size_t)blockIdx.x * 4096;

    #pragma unroll
    for (int i = 0; i < 4; ++i) {
        const int f  = t + i * 256;
        const int ld = (f >> 4) * 68 + (f & 15) * 4;
        float4 a = *(const float4*)(k + base + f * 4);
        a.x = elu1(a.x); a.y = elu1(a.y); a.z = elu1(a.z); a.w = elu1(a.w);
        *(float4*)&Ls[ld] = a;
        *(float4*)&Lv[ld] = *(const float4*)(v + base + f * 4);
    }
    __syncthreads();

    float mu[4][4] = {{0.f}};
    #pragma unroll 4
    for (int s = 0; s < 64; ++s) {
        const float4 sk4 = *(const float4*)&Ls[s * 68 + r0];
        const float4 vv4 = *(const float4*)&Lv[s * 68 + c0];
        fma_col(mu, sk4.x, sk4.y, sk4.z, sk4.w, vv4);
    }
    #pragma unroll
    for (int i = 0; i < 4; ++i) {
        float4 o;
        o.x = mu[i][0]; o.y = mu[i][1]; o.z = mu[i][2]; o.w = mu[i][3];
        *(float4*)(Skv + base + (size_t)(r0 + i) * 64 + c0) = o;
    }
    if (t < 64) {
        float a = 0.f;
        #pragma unroll 8
        for (int s = 0; s < 64; ++s) a += Ls[s * 68 + t];
        zc[(size_t)blockIdx.x * 64 + t] = a;
    }
}

// ---- Stage 2: in-place EXCLUSIVE prefix over the 16 segments of each (b,h).
// grid (8, 128): x = row-group of 8 rows (512 floats), y = (b,h) chain.
__global__ __launch_bounds__(256)
void prefix_mem(float* __restrict__ Skv, float* __restrict__ zc) {
    const int t  = threadIdx.x;
    const int bh = blockIdx.y;
    float* p0 = Skv + (size_t)bh * 16 * 4096 + blockIdx.x * 512 + t * 2;
    float2 acc = make_float2(0.f, 0.f);
    #pragma unroll
    for (int n = 0; n < 16; ++n) {
        float2* p = (float2*)(p0 + (size_t)n * 4096);
        const float2 tmp = *p;
        *p = acc;
        acc.x += tmp.x; acc.y += tmp.y;
    }
    if (blockIdx.x == 0 && t < 64) {
        float* zp0 = zc + (size_t)bh * 16 * 64 + t;
        float za = 0.f;
        #pragma unroll
        for (int n = 0; n < 16; ++n) {
            float* zp = zp0 + n * 64;
            const float tmp = *zp;
            *zp = za;
            za += tmp;
        }
    }
}

// ---- Stage 3: per-segment attention output, fully parallel (2048 blocks).
// q tile is overwritten in place with attn.
__global__ __launch_bounds__(256)
void seg_attn(float* __restrict__ q, const float* __restrict__ k,
              const float* __restrict__ v, const float* __restrict__ memp,
              const float* __restrict__ zp, const float* __restrict__ beta) {
    __shared__ __align__(16) float Lq[64 * 68];   // raw q, later sigma_q
    __shared__ __align__(16) float Lk[64 * 68];   // raw k, later mem_n
    __shared__ __align__(16) float Lv[64 * 68];
    __shared__ __align__(16) float Lp[64 * 68];   // softmax P
    __shared__ float rs[64];                      // rowsum sigma_q
    __shared__ float zr[64];                      // z_n
    const int t  = threadIdx.x;
    const int tx = t & 15, ty = t >> 4;
    const int r0 = ty * 4, c0 = tx * 4;
    const int seg = blockIdx.x;
    const int h   = (seg >> 4) & 15;
    const float gate = 1.f / (1.f + __expf(-10.f * beta[h]));
    const float omg  = 1.f - gate;
    const size_t base = (size_t)seg * 4096;

    #pragma unroll
    for (int i = 0; i < 4; ++i) {
        const int f  = t + i * 256;
        const int ld = (f >> 4) * 68 + (f & 15) * 4;
        *(float4*)&Lq[ld] = *(const float4*)(q + base + f * 4);
        *(float4*)&Lk[ld] = *(const float4*)(k + base + f * 4);
        *(float4*)&Lv[ld] = *(const float4*)(v + base + f * 4);
    }
    if (t < 64) zr[t] = zp[base / 64 + t];        // seg*64 + t
    __syncthreads();

    // rowsum of sigma_q, from raw Lq with elu applied on read
    if (t < 64) {
        float s = 0.f;
        #pragma unroll
        for (int j = 0; j < 64; j += 4) {
            const float4 a = *(const float4*)&Lq[t * 68 + j];
            s += elu1(a.x) + elu1(a.y) + elu1(a.z) + elu1(a.w);
        }
        rs[t] = s;
    }
    // scores = q k^T, causal softmax (scale 1/8) -> Lp
    {
        float sc[4][4] = {{0.f}};
        #pragma unroll 4
        for (int kk = 0; kk < 64; kk += 4) {
            float4 aq0 = *(const float4*)&Lq[(r0 + 0) * 68 + kk];
            float4 aq1 = *(const float4*)&Lq[(r0 + 1) * 68 + kk];
            float4 aq2 = *(const float4*)&Lq[(r0 + 2) * 68 + kk];
            float4 aq3 = *(const float4*)&Lq[(r0 + 3) * 68 + kk];
            float4 bk0 = *(const float4*)&Lk[(c0 + 0) * 68 + kk];
            float4 bk1 = *(const float4*)&Lk[(c0 + 1) * 68 + kk];
            float4 bk2 = *(const float4*)&Lk[(c0 + 2) * 68 + kk];
            float4 bk3 = *(const float4*)&Lk[(c0 + 3) * 68 + kk];
            fma_col(sc, aq0.x, aq1.x, aq2.x, aq3.x, make_float4(bk0.x, bk1.x, bk2.x, bk3.x));
            fma_col(sc, aq0.y, aq1.y, aq2.y, aq3.y, make_float4(bk0.y, bk1.y, bk2.y, bk3.y));
            fma_col(sc, aq0.z, aq1.z, aq2.z, aq3.z, make_float4(bk0.z, bk1.z, bk2.z, bk3.z));
            fma_col(sc, aq0.w, aq1.w, aq2.w, aq3.w, make_float4(bk0.w, bk1.w, bk2.w, bk3.w));
        }
        #pragma unroll
        for (int i = 0; i < 4; ++i) {
            const int r = r0 + i;
            float m = -3.0e38f;
            #pragma unroll
            for (int j = 0; j < 4; ++j) {
                sc[i][j] = (c0 + j <= r) ? sc[i][j] * 0.125f : -3.0e38f;
                m = fmaxf(m, sc[i][j]);
            }
            #pragma unroll
            for (int off = 1; off < 16; off <<= 1)
                m = fmaxf(m, __shfl_xor(m, off, 64));
            float ssum = 0.f;
            #pragma unroll
            for (int j = 0; j < 4; ++j) {
                sc[i][j] = (c0 + j <= r) ? __expf(sc[i][j] - m) : 0.f;
                ssum += sc[i][j];
            }
            #pragma unroll
            for (int off = 1; off < 16; off <<= 1)
                ssum += __shfl_xor(ssum, off, 64);
            const float inv = 1.f / ssum;
            float4 p;
            p.x = sc[i][0] * inv; p.y = sc[i][1] * inv;
            p.z = sc[i][2] * inv; p.w = sc[i][3] * inv;
            *(float4*)&Lp[r * 68 + c0] = p;
        }
    }
    __syncthreads();
    // Lq -> sigma_q in place; Lk <- mem_n (raw k dead)
    #pragma unroll
    for (int i = 0; i < 4; ++i) {
        const int f  = t + i * 256;
        const int ld = (f >> 4) * 68 + (f & 15) * 4;
        float4 a = *(const float4*)&Lq[ld];
        a.x = elu1(a.x); a.y = elu1(a.y); a.z = elu1(a.z); a.w = elu1(a.w);
        *(float4*)&Lq[ld] = a;
        *(float4*)&Lk[ld] = *(const float4*)(memp + base + f * 4);
    }
    __syncthreads();
    // A_dot = P@V ; A_mem = sigma_q@mem / (rs*z + eps) ; combine ; store
    {
        float ad[4][4] = {{0.f}};
        #pragma unroll 4
        for (int c = 0; c < 64; ++c) {
            const float4 vv = *(const float4*)&Lv[c * 68 + c0];
            const float p0 = Lp[(r0 + 0) * 68 + c];
            const float p1 = Lp[(r0 + 1) * 68 + c];
            const float p2 = Lp[(r0 + 2) * 68 + c];
            const float p3 = Lp[(r0 + 3) * 68 + c];
            fma_col(ad, p0, p1, p2, p3, vv);
        }
        float am[4][4] = {{0.f}};
        #pragma unroll 4
        for (int kk = 0; kk < 64; kk += 4) {
            float4 a0 = *(const float4*)&Lq[(r0 + 0) * 68 + kk];
            float4 a1 = *(const float4*)&Lq[(r0 + 1) * 68 + kk];
            float4 a2 = *(const float4*)&Lq[(r0 + 2) * 68 + kk];
            float4 a3 = *(const float4*)&Lq[(r0 + 3) * 68 + kk];
            float4 m0 = *(const float4*)&Lk[(kk + 0) * 68 + c0];
            float4 m1 = *(const float4*)&Lk[(kk + 1) * 68 + c0];
            float4 m2 = *(const float4*)&Lk[(kk + 2) * 68 + c0];
            float4 m3 = *(const float4*)&Lk[(kk + 3) * 68 + c0];
            fma_col(am, a0.x, a1.x, a2.x, a3.x, m0);
            fma_col(am, a0.y, a1.y, a2.y, a3.y, m1);
            fma_col(am, a0.z, a1.z, a2.z, a3.z, m2);
            fma_col(am, a0.w, a1.w, a2.w, a3.w, m3);
        }
        const float4 z4 = *(const float4*)&zr[c0];
        #pragma unroll
        for (int i = 0; i < 4; ++i) {
            const float rsum = rs[r0 + i];
            float4 o;
            o.x = gate * (am[i][0] / (rsum * z4.x + 1e-6f)) + omg * ad[i][0];
            o.y = gate * (am[i][1] / (rsum * z4.y + 1e-6f)) + omg * ad[i][1];
            o.z = gate * (am[i][2] / (rsum * z4.z + 1e-6f)) + omg * ad[i][2];
            o.w = gate * (am[i][3] / (rsum * z4.w + 1e-6f)) + omg * ad[i][3];
            *(float4*)(q + base + (size_t)(r0 + i) * 64 + c0) = o;
        }
    }
}

extern "C" void kernel_launch(void* const* d_in, const int* in_sizes, int n_in,
                              void* d_out, int out_size, void* d_ws, size_t ws_size,
                              hipStream_t stream) {
    const float* x    = (const float*)d_in[0];
    const float* Wq   = (const float*)d_in[1];
    const float* bq   = (const float*)d_in[2];
    const float* Wk   = (const float*)d_in[3];
    const float* bk   = (const float*)d_in[4];
    const float* Wv   = (const float*)d_in[5];
    const float* bv   = (const float*)d_in[6];
    const float* Wo   = (const float*)d_in[7];
    const float* bo   = (const float*)d_in[8];
    const float* beta = (const float*)d_in[9];
    float* out = (float*)d_out;

    float* qb  = (float*)d_ws;                   // [8192][1024] -> becomes attn
    float* kb  = qb  + (size_t)MTOT * EE;
    float* vb  = kb  + (size_t)MTOT * EE;
    float* Skv = vb  + (size_t)MTOT * EE;        // 2048 x 4096 (Sk -> mem prefix)
    float* zc  = Skv + (size_t)2048 * 4096;      // 2048 x 64   (colsum -> z prefix)

    dim3 grid(EE / 128, MTOT / 128);
    gemm_mfma<2048><<<grid, 256, 0, stream>>>(x, Wq, bq, qb);
    gemm_mfma<2048><<<grid, 256, 0, stream>>>(x, Wk, bk, kb);
    gemm_mfma<2048><<<grid, 256, 0, stream>>>(x, Wv, bv, vb);
    seg_kv<<<2048, 256, 0, stream>>>(kb, vb, Skv, zc);
    prefix_mem<<<dim3(8, 128), 256, 0, stream>>>(Skv, zc);
    seg_attn<<<2048, 256, 0, stream>>>(qb, kb, vb, Skv, zc, beta);
    gemm_mfma<1024><<<grid, 256, 0, stream>>>(qb, Wo, bo, out);
}

// Round 4
// 397.474 us; speedup vs baseline: 4.9374x; 1.4892x over previous
//
#include <hip/hip_runtime.h>
#include <hip/hip_bf16.h>
#include <cstddef>

#define EE 1024            // E
#define MTOT 8192          // B*E

using floatx4 = __attribute__((ext_vector_type(4))) float;
using bf16x8  = __attribute__((ext_vector_type(8))) __bf16;

union FragU { uint4 u; bf16x8 b; };

__device__ __forceinline__ float elu1(float x) {
    return x > 0.f ? x + 1.f : __expf(x);
}

__device__ __forceinline__ unsigned int pack2bf(float x, float y) {
    __hip_bfloat162 h = __float22bfloat162_rn(make_float2(x, y));
    union { __hip_bfloat162 h; unsigned int u; } c;
    c.h = h;
    return c.u;
}

__device__ __forceinline__ uint4 pack8bf(const float4 a, const float4 b) {
    uint4 r;
    r.x = pack2bf(a.x, a.y); r.y = pack2bf(a.z, a.w);
    r.z = pack2bf(b.x, b.y); r.w = pack2bf(b.z, b.w);
    return r;
}

__device__ __forceinline__ unsigned short f2bf(float x) {
    union { __hip_bfloat16 h; unsigned short s; } c;
    c.h = __float2bfloat16(x);
    return c.s;
}

__device__ __forceinline__ void unp8(const uint4 p, float4& a, float4& b) {
    a.x = __uint_as_float(p.x << 16); a.y = __uint_as_float(p.x & 0xffff0000u);
    a.z = __uint_as_float(p.y << 16); a.w = __uint_as_float(p.y & 0xffff0000u);
    b.x = __uint_as_float(p.z << 16); b.y = __uint_as_float(p.z & 0xffff0000u);
    b.z = __uint_as_float(p.w << 16); b.w = __uint_as_float(p.w & 0xffff0000u);
}

__device__ __forceinline__ void ld_lds16(const unsigned short* g, unsigned short* l) {
    __builtin_amdgcn_global_load_lds(
        (const __attribute__((address_space(1))) void*)g,
        (__attribute__((address_space(3))) void*)l, 16, 0, 0);
}

// fp32 -> bf16 bulk convert, 8 elems/thread
__global__ __launch_bounds__(256)
void cvt_bf16(const float* __restrict__ src, unsigned short* __restrict__ dst, int n8) {
    const int i = blockIdx.x * 256 + threadIdx.x;
    if (i >= n8) return;
    const float4 a = ((const float4*)src)[2 * i];
    const float4 b = ((const float4*)src)[2 * i + 1];
    ((uint4*)dst)[i] = pack8bf(a, b);
}

// ---- m97-style MFMA core: bf16 A[M][K] x B[N][K]^T, 128x128 tile, BK=32,
// global_load_lds width-16 staging, unpadded row-major LDS [128][32].
template<int K>
__device__ __forceinline__ void mfma_core(const unsigned short* __restrict__ A,
                                          const unsigned short* __restrict__ B,
                                          int m0, int n0,
                                          unsigned short* As, unsigned short* Bs,
                                          floatx4 (&acc)[4][4]) {
    const int t = threadIdx.x;
    const int w = t >> 6, l = t & 63;
    const int wm = (w >> 1) * 64, wn = (w & 1) * 64;
    const int lm = l & 15, lq = l >> 4;
    const int ar = l >> 2;              // row within 16-row DMA chunk
    const int ac = (l & 3) * 8;         // k-offset (elems) within row
    const unsigned short* Ag0 = A + (size_t)(m0 + 32 * w + ar) * K + ac;
    const unsigned short* Ag1 = Ag0 + (size_t)16 * K;
    const unsigned short* Bg0 = B + (size_t)(n0 + 32 * w + ar) * K + ac;
    const unsigned short* Bg1 = Bg0 + (size_t)16 * K;
    unsigned short* Al0 = As + 1024 * w;          // byte 2048*w = chunk 2w
    unsigned short* Al1 = As + 1024 * w + 512;    // chunk 2w+1
    unsigned short* Bl0 = Bs + 1024 * w;
    unsigned short* Bl1 = Bs + 1024 * w + 512;

    for (int kb = 0; kb < K; kb += 32) {
        __syncthreads();                 // prior frag reads done before overwrite
        ld_lds16(Ag0 + kb, Al0);
        ld_lds16(Ag1 + kb, Al1);
        ld_lds16(Bg0 + kb, Bl0);
        ld_lds16(Bg1 + kb, Bl1);
        __syncthreads();                 // drains vmcnt -> LDS visible
        FragU af[4], bf[4];
        #pragma unroll
        for (int i = 0; i < 4; ++i)
            af[i].u = *(const uint4*)&As[(wm + i * 16 + lm) * 32 + lq * 8];
        #pragma unroll
        for (int j = 0; j < 4; ++j)
            bf[j].u = *(const uint4*)&Bs[(wn + j * 16 + lm) * 32 + lq * 8];
        #pragma unroll
        for (int i = 0; i < 4; ++i)
            #pragma unroll
            for (int j = 0; j < 4; ++j)
                acc[i][j] = __builtin_amdgcn_mfma_f32_16x16x32_bf16(
                    af[i].b, bf[j].b, acc[i][j], 0, 0, 0);
    }
}

// Fused QKV projection: A=xb [8192][2048], B=wb [3072][2048] (Wq|Wk|Wv rows).
// Writes q/k/v bf16 [8192][1024] each.
__global__ __launch_bounds__(256)
void gemm_qkv(const unsigned short* __restrict__ A, const unsigned short* __restrict__ B,
              const float* __restrict__ bq, const float* __restrict__ bk,
              const float* __restrict__ bv,
              unsigned short* __restrict__ qb, unsigned short* __restrict__ kb,
              unsigned short* __restrict__ vb) {
    __shared__ __align__(16) unsigned short As[128 * 32];
    __shared__ __align__(16) unsigned short Bs[128 * 32];
    const int m0 = blockIdx.y * 128;
    const int n0 = blockIdx.x * 128;
    floatx4 acc[4][4];
    #pragma unroll
    for (int i = 0; i < 4; ++i)
        #pragma unroll
        for (int j = 0; j < 4; ++j)
            acc[i][j] = (floatx4)(0.f);
    mfma_core<2048>(A, B, m0, n0, As, Bs, acc);

    const int t = threadIdx.x;
    const int w = t >> 6, l = t & 63;
    const int wm = (w >> 1) * 64, wn = (w & 1) * 64;
    const int lm = l & 15, lq = l >> 4;
    const int proj = n0 >> 10;                       // 0=q 1=k 2=v (tile never straddles)
    unsigned short* Cb = proj == 0 ? qb : (proj == 1 ? kb : vb);
    const float* bias  = proj == 0 ? bq : (proj == 1 ? bk : bv);
    const int nd = n0 & 1023;
    #pragma unroll
    for (int j = 0; j < 4; ++j) {
        const int d = nd + wn + j * 16 + lm;
        const float bj = bias[d];
        #pragma unroll
        for (int i = 0; i < 4; ++i) {
            #pragma unroll
            for (int r = 0; r < 4; ++r) {
                const int row = m0 + wm + i * 16 + lq * 4 + r;
                Cb[(size_t)row * 1024 + d] = f2bf(acc[i][j][r] + bj);
            }
        }
    }
}

// Output projection: A=attn bf16 [8192][1024], B=wob [1024][1024]. fp32 out.
__global__ __launch_bounds__(256)
void gemm_out(const unsigned short* __restrict__ A, const unsigned short* __restrict__ B,
              const float* __restrict__ bo, float* __restrict__ C) {
    __shared__ __align__(16) unsigned short As[128 * 32];
    __shared__ __align__(16) unsigned short Bs[128 * 32];
    const int m0 = blockIdx.y * 128;
    const int n0 = blockIdx.x * 128;
    floatx4 acc[4][4];
    #pragma unroll
    for (int i = 0; i < 4; ++i)
        #pragma unroll
        for (int j = 0; j < 4; ++j)
            acc[i][j] = (floatx4)(0.f);
    mfma_core<1024>(A, B, m0, n0, As, Bs, acc);

    const int t = threadIdx.x;
    const int w = t >> 6, l = t & 63;
    const int wm = (w >> 1) * 64, wn = (w & 1) * 64;
    const int lm = l & 15, lq = l >> 4;
    #pragma unroll
    for (int j = 0; j < 4; ++j) {
        const int col = n0 + wn + j * 16 + lm;
        const float bj = bo[col];
        #pragma unroll
        for (int i = 0; i < 4; ++i) {
            #pragma unroll
            for (int r = 0; r < 4; ++r) {
                const int row = m0 + wm + i * 16 + lq * 4 + r;
                C[(size_t)row * EE + col] = acc[i][j][r] + bj;
            }
        }
    }
}

__device__ __forceinline__ void fma_col(float (&acc)[4][4],
                                        float a0, float a1, float a2, float a3,
                                        const float4 b) {
    acc[0][0] += a0 * b.x; acc[0][1] += a0 * b.y; acc[0][2] += a0 * b.z; acc[0][3] += a0 * b.w;
    acc[1][0] += a1 * b.x; acc[1][1] += a1 * b.y; acc[1][2] += a1 * b.z; acc[1][3] += a1 * b.w;
    acc[2][0] += a2 * b.x; acc[2][1] += a2 * b.y; acc[2][2] += a2 * b.z; acc[2][3] += a2 * b.w;
    acc[3][0] += a3 * b.x; acc[3][1] += a3 * b.y; acc[3][2] += a3 * b.z; acc[3][3] += a3 * b.w;
}

// ---- Stage 1: per-segment Sk = sigma_k^T @ v and colsum(sigma_k). bf16 in.
__global__ __launch_bounds__(256)
void seg_kv(const unsigned short* __restrict__ k, const unsigned short* __restrict__ v,
            float* __restrict__ Skv, float* __restrict__ zc) {
    __shared__ __align__(16) float Ls[64 * 68];
    __shared__ __align__(16) float Lv[64 * 68];
    const int t  = threadIdx.x;
    const int tx = t & 15, ty = t >> 4;
    const int r0 = ty * 4, c0 = tx * 4;
    const size_t base = (size_t)blockIdx.x * 4096;

    #pragma unroll
    for (int i = 0; i < 2; ++i) {
        const int c = t + i * 256;            // 8-elem chunk
        const int s = c >> 3, d0 = (c & 7) * 8;
        const uint4 pk = *(const uint4*)(k + base + c * 8);
        const uint4 pv = *(const uint4*)(v + base + c * 8);
        float4 ka, kbv, va, vbv;
        unp8(pk, ka, kbv);
        unp8(pv, va, vbv);
        ka.x = elu1(ka.x); ka.y = elu1(ka.y); ka.z = elu1(ka.z); ka.w = elu1(ka.w);
        kbv.x = elu1(kbv.x); kbv.y = elu1(kbv.y); kbv.z = elu1(kbv.z); kbv.w = elu1(kbv.w);
        *(float4*)&Ls[s * 68 + d0]     = ka;
        *(float4*)&Ls[s * 68 + d0 + 4] = kbv;
        *(float4*)&Lv[s * 68 + d0]     = va;
        *(float4*)&Lv[s * 68 + d0 + 4] = vbv;
    }
    __syncthreads();

    float mu[4][4] = {{0.f}};
    #pragma unroll 4
    for (int s = 0; s < 64; ++s) {
        const float4 sk4 = *(const float4*)&Ls[s * 68 + r0];
        const float4 vv4 = *(const float4*)&Lv[s * 68 + c0];
        fma_col(mu, sk4.x, sk4.y, sk4.z, sk4.w, vv4);
    }
    #pragma unroll
    for (int i = 0; i < 4; ++i) {
        float4 o;
        o.x = mu[i][0]; o.y = mu[i][1]; o.z = mu[i][2]; o.w = mu[i][3];
        *(float4*)(Skv + base + (size_t)(r0 + i) * 64 + c0) = o;
    }
    if (t < 64) {
        float a = 0.f;
        #pragma unroll 8
        for (int s = 0; s < 64; ++s) a += Ls[s * 68 + t];
        zc[(size_t)blockIdx.x * 64 + t] = a;
    }
}

// ---- Stage 2: exclusive prefix over 16 segments per (b,h) chain.
__global__ __launch_bounds__(256)
void prefix_mem(float* __restrict__ Skv, float* __restrict__ zc) {
    const int t  = threadIdx.x;
    const int bh = blockIdx.y;
    float* p0 = Skv + (size_t)bh * 16 * 4096 + blockIdx.x * 512 + t * 2;
    float2 acc = make_float2(0.f, 0.f);
    #pragma unroll
    for (int n = 0; n < 16; ++n) {
        float2* p = (float2*)(p0 + (size_t)n * 4096);
        const float2 tmp = *p;
        *p = acc;
        acc.x += tmp.x; acc.y += tmp.y;
    }
    if (blockIdx.x == 0 && t < 64) {
        float* zp0 = zc + (size_t)bh * 16 * 64 + t;
        float za = 0.f;
        #pragma unroll
        for (int n = 0; n < 16; ++n) {
            float* zp = zp0 + n * 64;
            const float tmp = *zp;
            *zp = za;
            za += tmp;
        }
    }
}

// ---- Stage 3: per-segment attention; bf16 q/k/v in, bf16 attn out.
__global__ __launch_bounds__(256)
void seg_attn(const unsigned short* __restrict__ q, const unsigned short* __restrict__ k,
              const unsigned short* __restrict__ v, const float* __restrict__ memp,
              const float* __restrict__ zp, const float* __restrict__ beta,
              unsigned short* __restrict__ ab) {
    __shared__ __align__(16) float Lq[64 * 68];   // raw q, later sigma_q
    __shared__ __align__(16) float Lk[64 * 68];   // raw k, later mem_n
    __shared__ __align__(16) float Lv[64 * 68];
    __shared__ __align__(16) float Lp[64 * 68];
    __shared__ float rs[64];
    __shared__ float zr[64];
    const int t  = threadIdx.x;
    const int tx = t & 15, ty = t >> 4;
    const int r0 = ty * 4, c0 = tx * 4;
    const int seg = blockIdx.x;
    const int h   = (seg >> 4) & 15;
    const float gate = 1.f / (1.f + __expf(-10.f * beta[h]));
    const float omg  = 1.f - gate;
    const size_t base = (size_t)seg * 4096;

    #pragma unroll
    for (int i = 0; i < 2; ++i) {
        const int c = t + i * 256;
        const int s = c >> 3, d0 = (c & 7) * 8;
        float4 a, b;
        unp8(*(const uint4*)(q + base + c * 8), a, b);
        *(float4*)&Lq[s * 68 + d0] = a; *(float4*)&Lq[s * 68 + d0 + 4] = b;
        unp8(*(const uint4*)(k + base + c * 8), a, b);
        *(float4*)&Lk[s * 68 + d0] = a; *(float4*)&Lk[s * 68 + d0 + 4] = b;
        unp8(*(const uint4*)(v + base + c * 8), a, b);
        *(float4*)&Lv[s * 68 + d0] = a; *(float4*)&Lv[s * 68 + d0 + 4] = b;
    }
    if (t < 64) zr[t] = zp[(size_t)seg * 64 + t];
    __syncthreads();

    if (t < 64) {
        float s = 0.f;
        #pragma unroll
        for (int j = 0; j < 64; j += 4) {
            const float4 a = *(const float4*)&Lq[t * 68 + j];
            s += elu1(a.x) + elu1(a.y) + elu1(a.z) + elu1(a.w);
        }
        rs[t] = s;
    }
    {
        float sc[4][4] = {{0.f}};
        #pragma unroll 4
        for (int kk = 0; kk < 64; kk += 4) {
            float4 aq0 = *(const float4*)&Lq[(r0 + 0) * 68 + kk];
            float4 aq1 = *(const float4*)&Lq[(r0 + 1) * 68 + kk];
            float4 aq2 = *(const float4*)&Lq[(r0 + 2) * 68 + kk];
            float4 aq3 = *(const float4*)&Lq[(r0 + 3) * 68 + kk];
            float4 bk0 = *(const float4*)&Lk[(c0 + 0) * 68 + kk];
            float4 bk1 = *(const float4*)&Lk[(c0 + 1) * 68 + kk];
            float4 bk2 = *(const float4*)&Lk[(c0 + 2) * 68 + kk];
            float4 bk3 = *(const float4*)&Lk[(c0 + 3) * 68 + kk];
            fma_col(sc, aq0.x, aq1.x, aq2.x, aq3.x, make_float4(bk0.x, bk1.x, bk2.x, bk3.x));
            fma_col(sc, aq0.y, aq1.y, aq2.y, aq3.y, make_float4(bk0.y, bk1.y, bk2.y, bk3.y));
            fma_col(sc, aq0.z, aq1.z, aq2.z, aq3.z, make_float4(bk0.z, bk1.z, bk2.z, bk3.z));
            fma_col(sc, aq0.w, aq1.w, aq2.w, aq3.w, make_float4(bk0.w, bk1.w, bk2.w, bk3.w));
        }
        #pragma unroll
        for (int i = 0; i < 4; ++i) {
            const int r = r0 + i;
            float m = -3.0e38f;
            #pragma unroll
            for (int j = 0; j < 4; ++j) {
                sc[i][j] = (c0 + j <= r) ? sc[i][j] * 0.125f : -3.0e38f;
                m = fmaxf(m, sc[i][j]);
            }
            #pragma unroll
            for (int off = 1; off < 16; off <<= 1)
                m = fmaxf(m, __shfl_xor(m, off, 64));
            float ssum = 0.f;
            #pragma unroll
            for (int j = 0; j < 4; ++j) {
                sc[i][j] = (c0 + j <= r) ? __expf(sc[i][j] - m) : 0.f;
                ssum += sc[i][j];
            }
            #pragma unroll
            for (int off = 1; off < 16; off <<= 1)
                ssum += __shfl_xor(ssum, off, 64);
            const float inv = 1.f / ssum;
            float4 p;
            p.x = sc[i][0] * inv; p.y = sc[i][1] * inv;
            p.z = sc[i][2] * inv; p.w = sc[i][3] * inv;
            *(float4*)&Lp[r * 68 + c0] = p;
        }
    }
    __syncthreads();
    #pragma unroll
    for (int i = 0; i < 4; ++i) {
        const int f  = t + i * 256;
        const int ld = (f >> 4) * 68 + (f & 15) * 4;
        float4 a = *(const float4*)&Lq[ld];
        a.x = elu1(a.x); a.y = elu1(a.y); a.z = elu1(a.z); a.w = elu1(a.w);
        *(float4*)&Lq[ld] = a;
        *(float4*)&Lk[ld] = *(const float4*)(memp + base + f * 4);
    }
    __syncthreads();
    {
        float ad[4][4] = {{0.f}};
        #pragma unroll 4
        for (int c = 0; c < 64; ++c) {
            const float4 vv = *(const float4*)&Lv[c * 68 + c0];
            const float p0 = Lp[(r0 + 0) * 68 + c];
            const float p1 = Lp[(r0 + 1) * 68 + c];
            const float p2 = Lp[(r0 + 2) * 68 + c];
            const float p3 = Lp[(r0 + 3) * 68 + c];
            fma_col(ad, p0, p1, p2, p3, vv);
        }
        float am[4][4] = {{0.f}};
        #pragma unroll 4
        for (int kk = 0; kk < 64; kk += 4) {
            float4 a0 = *(const float4*)&Lq[(r0 + 0) * 68 + kk];
            float4 a1 = *(const float4*)&Lq[(r0 + 1) * 68 + kk];
            float4 a2 = *(const float4*)&Lq[(r0 + 2) * 68 + kk];
            float4 a3 = *(const float4*)&Lq[(r0 + 3) * 68 + kk];
            float4 m0 = *(const float4*)&Lk[(kk + 0) * 68 + c0];
            float4 m1 = *(const float4*)&Lk[(kk + 1) * 68 + c0];
            float4 m2 = *(const float4*)&Lk[(kk + 2) * 68 + c0];
            float4 m3 = *(const float4*)&Lk[(kk + 3) * 68 + c0];
            fma_col(am, a0.x, a1.x, a2.x, a3.x, m0);
            fma_col(am, a0.y, a1.y, a2.y, a3.y, m1);
            fma_col(am, a0.z, a1.z, a2.z, a3.z, m2);
            fma_col(am, a0.w, a1.w, a2.w, a3.w, m3);
        }
        const float4 z4 = *(const float4*)&zr[c0];
        #pragma unroll
        for (int i = 0; i < 4; ++i) {
            const float rsum = rs[r0 + i];
            float4 o;
            o.x = gate * (am[i][0] / (rsum * z4.x + 1e-6f)) + omg * ad[i][0];
            o.y = gate * (am[i][1] / (rsum * z4.y + 1e-6f)) + omg * ad[i][1];
            o.z = gate * (am[i][2] / (rsum * z4.z + 1e-6f)) + omg * ad[i][2];
            o.w = gate * (am[i][3] / (rsum * z4.w + 1e-6f)) + omg * ad[i][3];
            const unsigned int lo = pack2bf(o.x, o.y);
            const unsigned int hi = pack2bf(o.z, o.w);
            *(uint2*)(ab + base + (size_t)(r0 + i) * 64 + c0) = make_uint2(lo, hi);
        }
    }
}

extern "C" void kernel_launch(void* const* d_in, const int* in_sizes, int n_in,
                              void* d_out, int out_size, void* d_ws, size_t ws_size,
                              hipStream_t stream) {
    const float* x    = (const float*)d_in[0];
    const float* Wq   = (const float*)d_in[1];
    const float* bq   = (const float*)d_in[2];
    const float* Wk   = (const float*)d_in[3];
    const float* bk   = (const float*)d_in[4];
    const float* Wv   = (const float*)d_in[5];
    const float* bv   = (const float*)d_in[6];
    const float* Wo   = (const float*)d_in[7];
    const float* bo   = (const float*)d_in[8];
    const float* beta = (const float*)d_in[9];
    float* out = (float*)d_out;

    unsigned char* wsb = (unsigned char*)d_ws;
    unsigned short* xb  = (unsigned short*)(wsb);                       // 32 MB; reused as ab
    unsigned short* wb  = (unsigned short*)(wsb + (32ull << 20));       // 12 MB  [3072][2048]
    unsigned short* wob = (unsigned short*)(wsb + (44ull << 20));       // 2 MB   [1024][1024]
    unsigned short* qb  = (unsigned short*)(wsb + (46ull << 20));       // 16 MB
    unsigned short* kb  = (unsigned short*)(wsb + (62ull << 20));       // 16 MB
    unsigned short* vb  = (unsigned short*)(wsb + (78ull << 20));       // 16 MB
    float* Skv = (float*)(wsb + (94ull << 20));                         // 32 MB
    float* zc  = (float*)(wsb + (126ull << 20));                        // 0.5 MB
    unsigned short* ab = xb;   // attn bf16 (xb dead after gemm_qkv)

    cvt_bf16<<<8192, 256, 0, stream>>>(x, xb, 2097152);
    cvt_bf16<<<1024, 256, 0, stream>>>(Wq, wb,           262144);
    cvt_bf16<<<1024, 256, 0, stream>>>(Wk, wb + 2097152, 262144);
    cvt_bf16<<<1024, 256, 0, stream>>>(Wv, wb + 4194304, 262144);
    cvt_bf16<<<512,  256, 0, stream>>>(Wo, wob,          131072);

    gemm_qkv<<<dim3(24, 64), 256, 0, stream>>>(xb, wb, bq, bk, bv, qb, kb, vb);
    seg_kv<<<2048, 256, 0, stream>>>(kb, vb, Skv, zc);
    prefix_mem<<<dim3(8, 128), 256, 0, stream>>>(Skv, zc);
    seg_attn<<<2048, 256, 0, stream>>>(qb, kb, vb, Skv, zc, beta, ab);
    gemm_out<<<dim3(8, 64), 256, 0, stream>>>(ab, wob, bo, out);
}

// Round 5
// 338.069 us; speedup vs baseline: 5.8049x; 1.1757x over previous
//
#include <hip/hip_runtime.h>
#include <hip/hip_bf16.h>
#include <cstddef>

#define EE 1024            // E
#define MTOT 8192          // B*E

using floatx4 = __attribute__((ext_vector_type(4))) float;
using bf16x8  = __attribute__((ext_vector_type(8))) __bf16;

union FragU { uint4 u; bf16x8 b; };

__device__ __forceinline__ float elu1(float x) {
    return x > 0.f ? x + 1.f : __expf(x);
}

__device__ __forceinline__ unsigned int pack2bf(float x, float y) {
    __hip_bfloat162 h = __float22bfloat162_rn(make_float2(x, y));
    union { __hip_bfloat162 h; unsigned int u; } c;
    c.h = h;
    return c.u;
}

__device__ __forceinline__ uint4 pack8bf(const float4 a, const float4 b) {
    uint4 r;
    r.x = pack2bf(a.x, a.y); r.y = pack2bf(a.z, a.w);
    r.z = pack2bf(b.x, b.y); r.w = pack2bf(b.z, b.w);
    return r;
}

__device__ __forceinline__ unsigned short f2bf(float x) {
    union { __hip_bfloat16 h; unsigned short s; } c;
    c.h = __float2bfloat16(x);
    return c.s;
}

__device__ __forceinline__ void unp8(const uint4 p, float4& a, float4& b) {
    a.x = __uint_as_float(p.x << 16); a.y = __uint_as_float(p.x & 0xffff0000u);
    a.z = __uint_as_float(p.y << 16); a.w = __uint_as_float(p.y & 0xffff0000u);
    b.x = __uint_as_float(p.z << 16); b.y = __uint_as_float(p.z & 0xffff0000u);
    b.z = __uint_as_float(p.w << 16); b.w = __uint_as_float(p.w & 0xffff0000u);
}

__device__ __forceinline__ void ld_lds16(const unsigned short* g, unsigned short* l) {
    __builtin_amdgcn_global_load_lds(
        (const __attribute__((address_space(1))) void*)g,
        (__attribute__((address_space(3))) void*)l, 16, 0, 0);
}

// fp32 -> bf16 bulk convert, 8 elems/thread
__global__ __launch_bounds__(256)
void cvt_bf16(const float* __restrict__ src, unsigned short* __restrict__ dst, int n8) {
    const int i = blockIdx.x * 256 + threadIdx.x;
    if (i >= n8) return;
    const float4 a = ((const float4*)src)[2 * i];
    const float4 b = ((const float4*)src)[2 * i + 1];
    ((uint4*)dst)[i] = pack8bf(a, b);
}

// All four weight matrices in one launch. Regions (uint4-chunk counts):
// Wq 262144 | Wk 262144 | Wv 262144 | Wo 131072 -> 917504 chunks total.
__global__ __launch_bounds__(256)
void cvt_w(const float* __restrict__ Wq, const float* __restrict__ Wk,
           const float* __restrict__ Wv, const float* __restrict__ Wo,
           unsigned short* __restrict__ wb, unsigned short* __restrict__ wob) {
    const int i = blockIdx.x * 256 + threadIdx.x;
    if (i >= 917504) return;
    const float* src;
    unsigned short* dst;
    int off;
    if (i < 262144)      { src = Wq; dst = wb;           off = i; }
    else if (i < 524288) { src = Wk; dst = wb + 2097152; off = i - 262144; }
    else if (i < 786432) { src = Wv; dst = wb + 4194304; off = i - 524288; }
    else                 { src = Wo; dst = wob;          off = i - 786432; }
    const float4 a = ((const float4*)src)[2 * off];
    const float4 b = ((const float4*)src)[2 * off + 1];
    ((uint4*)dst)[off] = pack8bf(a, b);
}

// ---- m97-style MFMA core: bf16 A[M][K] x B[N][K]^T, 128x128 tile, BK=32,
// global_load_lds width-16 staging, unpadded row-major LDS [128][32].
template<int K>
__device__ __forceinline__ void mfma_core(const unsigned short* __restrict__ A,
                                          const unsigned short* __restrict__ B,
                                          int m0, int n0,
                                          unsigned short* As, unsigned short* Bs,
                                          floatx4 (&acc)[4][4]) {
    const int t = threadIdx.x;
    const int w = t >> 6, l = t & 63;
    const int wm = (w >> 1) * 64, wn = (w & 1) * 64;
    const int lm = l & 15, lq = l >> 4;
    const int ar = l >> 2;
    const int ac = (l & 3) * 8;
    const unsigned short* Ag0 = A + (size_t)(m0 + 32 * w + ar) * K + ac;
    const unsigned short* Ag1 = Ag0 + (size_t)16 * K;
    const unsigned short* Bg0 = B + (size_t)(n0 + 32 * w + ar) * K + ac;
    const unsigned short* Bg1 = Bg0 + (size_t)16 * K;
    unsigned short* Al0 = As + 1024 * w;
    unsigned short* Al1 = As + 1024 * w + 512;
    unsigned short* Bl0 = Bs + 1024 * w;
    unsigned short* Bl1 = Bs + 1024 * w + 512;

    for (int kb = 0; kb < K; kb += 32) {
        __syncthreads();
        ld_lds16(Ag0 + kb, Al0);
        ld_lds16(Ag1 + kb, Al1);
        ld_lds16(Bg0 + kb, Bl0);
        ld_lds16(Bg1 + kb, Bl1);
        __syncthreads();
        FragU af[4], bf[4];
        #pragma unroll
        for (int i = 0; i < 4; ++i)
            af[i].u = *(const uint4*)&As[(wm + i * 16 + lm) * 32 + lq * 8];
        #pragma unroll
        for (int j = 0; j < 4; ++j)
            bf[j].u = *(const uint4*)&Bs[(wn + j * 16 + lm) * 32 + lq * 8];
        #pragma unroll
        for (int i = 0; i < 4; ++i)
            #pragma unroll
            for (int j = 0; j < 4; ++j)
                acc[i][j] = __builtin_amdgcn_mfma_f32_16x16x32_bf16(
                    af[i].b, bf[j].b, acc[i][j], 0, 0, 0);
    }
}

// Fused QKV projection: A=xb [8192][2048], B=wb [3072][2048] (Wq|Wk|Wv rows).
__global__ __launch_bounds__(256)
void gemm_qkv(const unsigned short* __restrict__ A, const unsigned short* __restrict__ B,
              const float* __restrict__ bq, const float* __restrict__ bk,
              const float* __restrict__ bv,
              unsigned short* __restrict__ qb, unsigned short* __restrict__ kb,
              unsigned short* __restrict__ vb) {
    __shared__ __align__(16) unsigned short As[128 * 32];
    __shared__ __align__(16) unsigned short Bs[128 * 32];
    const int m0 = blockIdx.y * 128;
    const int n0 = blockIdx.x * 128;
    floatx4 acc[4][4];
    #pragma unroll
    for (int i = 0; i < 4; ++i)
        #pragma unroll
        for (int j = 0; j < 4; ++j)
            acc[i][j] = (floatx4)(0.f);
    mfma_core<2048>(A, B, m0, n0, As, Bs, acc);

    const int t = threadIdx.x;
    const int w = t >> 6, l = t & 63;
    const int wm = (w >> 1) * 64, wn = (w & 1) * 64;
    const int lm = l & 15, lq = l >> 4;
    const int proj = n0 >> 10;
    unsigned short* Cb = proj == 0 ? qb : (proj == 1 ? kb : vb);
    const float* bias  = proj == 0 ? bq : (proj == 1 ? bk : bv);
    const int nd = n0 & 1023;
    #pragma unroll
    for (int j = 0; j < 4; ++j) {
        const int d = nd + wn + j * 16 + lm;
        const float bj = bias[d];
        #pragma unroll
        for (int i = 0; i < 4; ++i) {
            #pragma unroll
            for (int r = 0; r < 4; ++r) {
                const int row = m0 + wm + i * 16 + lq * 4 + r;
                Cb[(size_t)row * 1024 + d] = f2bf(acc[i][j][r] + bj);
            }
        }
    }
}

// Output projection: A=attn bf16 [8192][1024], B=wob [1024][1024]. fp32 out.
__global__ __launch_bounds__(256)
void gemm_out(const unsigned short* __restrict__ A, const unsigned short* __restrict__ B,
              const float* __restrict__ bo, float* __restrict__ C) {
    __shared__ __align__(16) unsigned short As[128 * 32];
    __shared__ __align__(16) unsigned short Bs[128 * 32];
    const int m0 = blockIdx.y * 128;
    const int n0 = blockIdx.x * 128;
    floatx4 acc[4][4];
    #pragma unroll
    for (int i = 0; i < 4; ++i)
        #pragma unroll
        for (int j = 0; j < 4; ++j)
            acc[i][j] = (floatx4)(0.f);
    mfma_core<1024>(A, B, m0, n0, As, Bs, acc);

    const int t = threadIdx.x;
    const int w = t >> 6, l = t & 63;
    const int wm = (w >> 1) * 64, wn = (w & 1) * 64;
    const int lm = l & 15, lq = l >> 4;
    #pragma unroll
    for (int j = 0; j < 4; ++j) {
        const int col = n0 + wn + j * 16 + lm;
        const float bj = bo[col];
        #pragma unroll
        for (int i = 0; i < 4; ++i) {
            #pragma unroll
            for (int r = 0; r < 4; ++r) {
                const int row = m0 + wm + i * 16 + lq * 4 + r;
                C[(size_t)row * EE + col] = acc[i][j][r] + bj;
            }
        }
    }
}

// ---- Stage 1 (MFMA): Sk[d][e] = sum_s sigma_k[s][d]*v[s][e], z[d]=colsum(sigma_k).
// One block per segment tile. sigma_k^T and v^T staged transposed in LDS so both
// MFMA operand frags are contiguous ds_read_b128.
__global__ __launch_bounds__(256)
void seg_kv(const unsigned short* __restrict__ k, const unsigned short* __restrict__ v,
            float* __restrict__ Skv, float* __restrict__ zc) {
    __shared__ __align__(16) unsigned short KT[64 * 72];  // sigma_k^T [d][s]
    __shared__ __align__(16) unsigned short VT[64 * 72];  // v^T       [e][s]
    const int t = threadIdx.x;
    const int w = t >> 6, l = t & 63, quad = l >> 4, lm = l & 15;
    const size_t base = (size_t)blockIdx.x * 4096;

    #pragma unroll
    for (int i = 0; i < 2; ++i) {
        const int c  = t + i * 256;            // uint4 chunk
        const int sr = c >> 3, c0 = (c & 7) * 8;
        const uint4 pk = *(const uint4*)(k + base + c * 8);
        const uint4 pv = *(const uint4*)(v + base + c * 8);
        float4 f0, f1;
        unp8(pk, f0, f1);
        KT[(c0 + 0) * 72 + sr] = f2bf(elu1(f0.x));
        KT[(c0 + 1) * 72 + sr] = f2bf(elu1(f0.y));
        KT[(c0 + 2) * 72 + sr] = f2bf(elu1(f0.z));
        KT[(c0 + 3) * 72 + sr] = f2bf(elu1(f0.w));
        KT[(c0 + 4) * 72 + sr] = f2bf(elu1(f1.x));
        KT[(c0 + 5) * 72 + sr] = f2bf(elu1(f1.y));
        KT[(c0 + 6) * 72 + sr] = f2bf(elu1(f1.z));
        KT[(c0 + 7) * 72 + sr] = f2bf(elu1(f1.w));
        const unsigned short* pvs = (const unsigned short*)&pv;
        #pragma unroll
        for (int jj = 0; jj < 8; ++jj) VT[(c0 + jj) * 72 + sr] = pvs[jj];
    }
    __syncthreads();

    if (t < 64) {                                  // z[d] = rowsum of KT row d
        float ssum = 0.f;
        #pragma unroll
        for (int c2 = 0; c2 < 8; ++c2) {
            const uint4 p = *(const uint4*)&KT[t * 72 + c2 * 8];
            float4 a, b;
            unp8(p, a, b);
            ssum += a.x + a.y + a.z + a.w + b.x + b.y + b.z + b.w;
        }
        zc[(size_t)blockIdx.x * 64 + t] = ssum;
    }

    FragU ak0, ak1;
    ak0.u = *(const uint4*)&KT[(16 * w + lm) * 72 + quad * 8];
    ak1.u = *(const uint4*)&KT[(16 * w + lm) * 72 + 32 + quad * 8];
    floatx4 C4[4];
    #pragma unroll
    for (int j = 0; j < 4; ++j) C4[j] = (floatx4)(0.f);
    #pragma unroll
    for (int j = 0; j < 4; ++j) {
        FragU b0, b1;
        b0.u = *(const uint4*)&VT[(j * 16 + lm) * 72 + quad * 8];
        b1.u = *(const uint4*)&VT[(j * 16 + lm) * 72 + 32 + quad * 8];
        C4[j] = __builtin_amdgcn_mfma_f32_16x16x32_bf16(ak0.b, b0.b, C4[j], 0, 0, 0);
        C4[j] = __builtin_amdgcn_mfma_f32_16x16x32_bf16(ak1.b, b1.b, C4[j], 0, 0, 0);
    }
    const int d0 = 16 * w + quad * 4;
    #pragma unroll
    for (int j = 0; j < 4; ++j)
        #pragma unroll
        for (int r = 0; r < 4; ++r)
            Skv[base + (size_t)(d0 + r) * 64 + j * 16 + lm] = C4[j][r];
}

// ---- Stage 2: exclusive prefix over 16 segments per (b,h) chain.
__global__ __launch_bounds__(256)
void prefix_mem(float* __restrict__ Skv, float* __restrict__ zc) {
    const int t  = threadIdx.x;
    const int bh = blockIdx.y;
    float* p0 = Skv + (size_t)bh * 16 * 4096 + blockIdx.x * 512 + t * 2;
    float2 acc = make_float2(0.f, 0.f);
    #pragma unroll
    for (int n = 0; n < 16; ++n) {
        float2* p = (float2*)(p0 + (size_t)n * 4096);
        const float2 tmp = *p;
        *p = acc;
        acc.x += tmp.x; acc.y += tmp.y;
    }
    if (blockIdx.x == 0 && t < 64) {
        float* zp0 = zc + (size_t)bh * 16 * 64 + t;
        float za = 0.f;
        #pragma unroll
        for (int n = 0; n < 16; ++n) {
            float* zp = zp0 + n * 64;
            const float tmp = *zp;
            *zp = za;
            za += tmp;
        }
    }
}

// ---- Stage 3 (MFMA): per-segment attention. Scores/P@V/sigma_q@mem all on MFMA.
// q,k frags direct from global (row-major = natural A/B^T layout); v^T, mem^T
// staged in LDS; P round-trips through LDS (C-layout -> A-layout).
__global__ __launch_bounds__(256)
void seg_attn(const unsigned short* __restrict__ q, const unsigned short* __restrict__ k,
              const unsigned short* __restrict__ v, const float* __restrict__ memp,
              const float* __restrict__ zp, const float* __restrict__ beta,
              unsigned short* __restrict__ ab) {
    __shared__ __align__(16) unsigned short Pb[64 * 72];  // P bf16 [s][t]
    __shared__ __align__(16) unsigned short VT[64 * 72];  // v^T    [e][s]
    __shared__ __align__(16) unsigned short MT[64 * 72];  // mem^T  [e][d]
    __shared__ float rs[64];
    __shared__ float zr[64];
    const int t = threadIdx.x;
    const int w = t >> 6, l = t & 63, quad = l >> 4, lm = l & 15;
    const int seg = blockIdx.x;
    const int h   = (seg >> 4) & 15;
    const float gate = 1.f / (1.f + __expf(-10.f * beta[h]));
    const float omg  = 1.f - gate;
    const size_t base = (size_t)seg * 4096;

    // stage v^T
    #pragma unroll
    for (int i = 0; i < 2; ++i) {
        const int c  = t + i * 256;
        const int sr = c >> 3, c0 = (c & 7) * 8;
        const uint4 pv = *(const uint4*)(v + base + c * 8);
        const unsigned short* pvs = (const unsigned short*)&pv;
        #pragma unroll
        for (int jj = 0; jj < 8; ++jj) VT[(c0 + jj) * 72 + sr] = pvs[jj];
    }
    // stage mem^T (fp32 -> bf16)
    #pragma unroll
    for (int i = 0; i < 4; ++i) {
        const int c = t + i * 256;               // float4 chunk
        const int d = c >> 4, e0 = (c & 15) * 4;
        const float4 m4 = *(const float4*)(memp + base + c * 4);
        MT[(e0 + 0) * 72 + d] = f2bf(m4.x);
        MT[(e0 + 1) * 72 + d] = f2bf(m4.y);
        MT[(e0 + 2) * 72 + d] = f2bf(m4.z);
        MT[(e0 + 3) * 72 + d] = f2bf(m4.w);
    }
    // rs[s] = rowsum(sigma_q): quarter-row per thread + shfl reduce
    {
        const int s = t >> 2, dq = (t & 3) * 16;
        const uint4 a0 = *(const uint4*)(q + base + s * 64 + dq);
        const uint4 a1 = *(const uint4*)(q + base + s * 64 + dq + 8);
        float4 f0, f1, f2, f3;
        unp8(a0, f0, f1); unp8(a1, f2, f3);
        float p = elu1(f0.x) + elu1(f0.y) + elu1(f0.z) + elu1(f0.w)
                + elu1(f1.x) + elu1(f1.y) + elu1(f1.z) + elu1(f1.w)
                + elu1(f2.x) + elu1(f2.y) + elu1(f2.z) + elu1(f2.w)
                + elu1(f3.x) + elu1(f3.y) + elu1(f3.z) + elu1(f3.w);
        p += __shfl_xor(p, 1, 64);
        p += __shfl_xor(p, 2, 64);
        if ((t & 3) == 0) rs[s] = p;
    }
    if (t < 64) zr[t] = zp[(size_t)seg * 64 + t];
    __syncthreads();

    // ---- scores: wave w computes rows [16w,16w+16) x all 64 cols
    const unsigned short* qrow = q + base + (size_t)(16 * w + lm) * 64;
    FragU aq0, aq1;
    aq0.u = *(const uint4*)(qrow + quad * 8);
    aq1.u = *(const uint4*)(qrow + 32 + quad * 8);
    floatx4 S[4];
    #pragma unroll
    for (int j = 0; j < 4; ++j) S[j] = (floatx4)(0.f);
    #pragma unroll
    for (int j = 0; j < 4; ++j) {
        const unsigned short* krow = k + base + (size_t)(j * 16 + lm) * 64;
        FragU b0, b1;
        b0.u = *(const uint4*)(krow + quad * 8);
        b1.u = *(const uint4*)(krow + 32 + quad * 8);
        S[j] = __builtin_amdgcn_mfma_f32_16x16x32_bf16(aq0.b, b0.b, S[j], 0, 0, 0);
        S[j] = __builtin_amdgcn_mfma_f32_16x16x32_bf16(aq1.b, b1.b, S[j], 0, 0, 0);
    }
    // ---- causal softmax in C-layout registers; write P bf16 to LDS
    const int srow0 = 16 * w + quad * 4;
    #pragma unroll
    for (int r = 0; r < 4; ++r) {
        const int s_g = srow0 + r;
        float m = -3.0e38f;
        #pragma unroll
        for (int j = 0; j < 4; ++j) {
            const int t_g = j * 16 + lm;
            const float val = (t_g <= s_g) ? S[j][r] * 0.125f : -3.0e38f;
            S[j][r] = val;
            m = fmaxf(m, val);
        }
        m = fmaxf(m, __shfl_xor(m, 1, 64));
        m = fmaxf(m, __shfl_xor(m, 2, 64));
        m = fmaxf(m, __shfl_xor(m, 4, 64));
        m = fmaxf(m, __shfl_xor(m, 8, 64));
        float ss = 0.f;
        #pragma unroll
        for (int j = 0; j < 4; ++j) {
            const int t_g = j * 16 + lm;
            const float e = (t_g <= s_g) ? __expf(S[j][r] - m) : 0.f;
            S[j][r] = e;
            ss += e;
        }
        ss += __shfl_xor(ss, 1, 64);
        ss += __shfl_xor(ss, 2, 64);
        ss += __shfl_xor(ss, 4, 64);
        ss += __shfl_xor(ss, 8, 64);
        const float inv = 1.f / ss;
        #pragma unroll
        for (int j = 0; j < 4; ++j)
            Pb[s_g * 72 + j * 16 + lm] = f2bf(S[j][r] * inv);
    }
    __syncthreads();

    // ---- A_dot = P@V and A_mem = sigma_q@mem (both C-layout accumulators)
    FragU ap0, ap1, as0, as1;
    ap0.u = *(const uint4*)&Pb[(16 * w + lm) * 72 + quad * 8];
    ap1.u = *(const uint4*)&Pb[(16 * w + lm) * 72 + 32 + quad * 8];
    {
        float4 f0, f1, f2, f3;
        unp8(aq0.u, f0, f1);
        unp8(aq1.u, f2, f3);
        f0.x = elu1(f0.x); f0.y = elu1(f0.y); f0.z = elu1(f0.z); f0.w = elu1(f0.w);
        f1.x = elu1(f1.x); f1.y = elu1(f1.y); f1.z = elu1(f1.z); f1.w = elu1(f1.w);
        f2.x = elu1(f2.x); f2.y = elu1(f2.y); f2.z = elu1(f2.z); f2.w = elu1(f2.w);
        f3.x = elu1(f3.x); f3.y = elu1(f3.y); f3.z = elu1(f3.z); f3.w = elu1(f3.w);
        as0.u = pack8bf(f0, f1);
        as1.u = pack8bf(f2, f3);
    }
    floatx4 AD[4], AM[4];
    #pragma unroll
    for (int j = 0; j < 4; ++j) { AD[j] = (floatx4)(0.f); AM[j] = (floatx4)(0.f); }
    #pragma unroll
    for (int j = 0; j < 4; ++j) {
        FragU bv0, bv1, bm0, bm1;
        bv0.u = *(const uint4*)&VT[(j * 16 + lm) * 72 + quad * 8];
        bv1.u = *(const uint4*)&VT[(j * 16 + lm) * 72 + 32 + quad * 8];
        bm0.u = *(const uint4*)&MT[(j * 16 + lm) * 72 + quad * 8];
        bm1.u = *(const uint4*)&MT[(j * 16 + lm) * 72 + 32 + quad * 8];
        AD[j] = __builtin_amdgcn_mfma_f32_16x16x32_bf16(ap0.b, bv0.b, AD[j], 0, 0, 0);
        AD[j] = __builtin_amdgcn_mfma_f32_16x16x32_bf16(ap1.b, bv1.b, AD[j], 0, 0, 0);
        AM[j] = __builtin_amdgcn_mfma_f32_16x16x32_bf16(as0.b, bm0.b, AM[j], 0, 0, 0);
        AM[j] = __builtin_amdgcn_mfma_f32_16x16x32_bf16(as1.b, bm1.b, AM[j], 0, 0, 0);
    }
    // ---- combine + store attn bf16
    #pragma unroll
    for (int j = 0; j < 4; ++j) {
        const int d = j * 16 + lm;
        const float zd = zr[d];
        #pragma unroll
        for (int r = 0; r < 4; ++r) {
            const int s_g = srow0 + r;
            const float den = rs[s_g] * zd + 1e-6f;
            const float o = gate * (AM[j][r] / den) + omg * AD[j][r];
            ab[base + (size_t)s_g * 64 + d] = f2bf(o);
        }
    }
}

extern "C" void kernel_launch(void* const* d_in, const int* in_sizes, int n_in,
                              void* d_out, int out_size, void* d_ws, size_t ws_size,
                              hipStream_t stream) {
    const float* x    = (const float*)d_in[0];
    const float* Wq   = (const float*)d_in[1];
    const float* bq   = (const float*)d_in[2];
    const float* Wk   = (const float*)d_in[3];
    const float* bk   = (const float*)d_in[4];
    const float* Wv   = (const float*)d_in[5];
    const float* bv   = (const float*)d_in[6];
    const float* Wo   = (const float*)d_in[7];
    const float* bo   = (const float*)d_in[8];
    const float* beta = (const float*)d_in[9];
    float* out = (float*)d_out;

    unsigned char* wsb = (unsigned char*)d_ws;
    unsigned short* xb  = (unsigned short*)(wsb);                       // 32 MB; reused as ab
    unsigned short* wb  = (unsigned short*)(wsb + (32ull << 20));       // 12 MB  [3072][2048]
    unsigned short* wob = (unsigned short*)(wsb + (44ull << 20));       // 2 MB   [1024][1024]
    unsigned short* qb  = (unsigned short*)(wsb + (46ull << 20));       // 16 MB
    unsigned short* kb  = (unsigned short*)(wsb + (62ull << 20));       // 16 MB
    unsigned short* vb  = (unsigned short*)(wsb + (78ull << 20));       // 16 MB
    float* Skv = (float*)(wsb + (94ull << 20));                         // 32 MB
    float* zc  = (float*)(wsb + (126ull << 20));                        // 0.5 MB
    unsigned short* ab = xb;   // attn bf16 (xb dead after gemm_qkv)

    cvt_bf16<<<8192, 256, 0, stream>>>(x, xb, 2097152);
    cvt_w<<<3584, 256, 0, stream>>>(Wq, Wk, Wv, Wo, wb, wob);

    gemm_qkv<<<dim3(24, 64), 256, 0, stream>>>(xb, wb, bq, bk, bv, qb, kb, vb);
    seg_kv<<<2048, 256, 0, stream>>>(kb, vb, Skv, zc);
    prefix_mem<<<dim3(8, 128), 256, 0, stream>>>(Skv, zc);
    seg_attn<<<2048, 256, 0, stream>>>(qb, kb, vb, Skv, zc, beta, ab);
    gemm_out<<<dim3(8, 64), 256, 0, stream>>>(ab, wob, bo, out);
}